// Round 1
// baseline (150.400 us; speedup 1.0000x reference)
//
#include <hip/hip_runtime.h>

// B=32, T=2048, D=64, K=4, KD=256
// out[b,t,j] = m*ha + (1-m)*(g*h_fwd + (1-g)*ha)
//   d = j % 64, m = M[b,t,d], delta = deltas[b,t,d]
//   g = exp(-relu(delta*W[j] + b[j]))
//   h_fwd = h_a[b, t-(int(delta)-1), j]
//
// One thread per float4 of the 256-wide inner row. A wave (64 lanes) covers
// exactly one (b,t) row: M/deltas re-reads across k are same-wave L1 hits.

#define TD_T 2048
#define TD_KD 256
#define TD_D 64

__global__ __launch_bounds__(256) void TemporalDecay_89524298318172_kernel(
    const float* __restrict__ h_a,
    const float* __restrict__ deltas,
    const float* __restrict__ M,
    const float* __restrict__ W,
    const float* __restrict__ bias,
    float* __restrict__ out)
{
    const int gid = blockIdx.x * blockDim.x + threadIdx.x;
    const int q   = gid & 63;        // which float4 within the 256-wide row
    const int row = gid >> 6;        // b*T + t
    const int t   = row & (TD_T - 1);
    const int b   = row >> 11;       // row / 2048
    const int j0  = q << 2;          // 0..252, multiple of 4
    const int d0  = j0 & (TD_D - 1); // no wrap inside a float4 (4 | 64)

    const size_t row_off = (size_t)row * TD_KD + j0;

    const float4 ha4 = *(const float4*)(h_a    + row_off);
    const float4 m4  = *(const float4*)(M      + (size_t)row * TD_D + d0);
    const float4 dl4 = *(const float4*)(deltas + (size_t)row * TD_D + d0);
    const float4 w4  = *(const float4*)(W    + j0);
    const float4 b4  = *(const float4*)(bias + j0);

    const float hv[4] = {ha4.x, ha4.y, ha4.z, ha4.w};
    const float mv[4] = {m4.x,  m4.y,  m4.z,  m4.w};
    const float dv[4] = {dl4.x, dl4.y, dl4.z, dl4.w};
    const float wv[4] = {w4.x,  w4.y,  w4.z,  w4.w};
    const float bv[4] = {b4.x,  b4.y,  b4.z,  b4.w};

    const float* batch_base = h_a + (size_t)b * TD_T * TD_KD;

    float res[4];
#pragma unroll
    for (int e = 0; e < 4; ++e) {
        const float delta = dv[e];
        const float g = __expf(-fmaxf(fmaf(delta, wv[e], bv[e]), 0.0f));
        const int idx = t - (int)delta + 1;            // in [t-3, t], >= 0
        const float hf = batch_base[(size_t)idx * TD_KD + j0 + e];
        const float m = mv[e];
        res[e] = m * hv[e] + (1.0f - m) * (g * hf + (1.0f - g) * hv[e]);
    }

    *(float4*)(out + row_off) = make_float4(res[0], res[1], res[2], res[3]);
}

extern "C" void kernel_launch(void* const* d_in, const int* in_sizes, int n_in,
                              void* d_out, int out_size, void* d_ws, size_t ws_size,
                              hipStream_t stream) {
    const float* h_a    = (const float*)d_in[0];
    const float* deltas = (const float*)d_in[1];
    const float* M      = (const float*)d_in[2];
    const float* W      = (const float*)d_in[3];
    const float* bias   = (const float*)d_in[4];
    float* out          = (float*)d_out;

    // total float4 threads = B*T*KD/4 = 32*2048*64 = 4,194,304
    const int total = in_sizes[0] / 4;
    const int block = 256;
    const int grid = (total + block - 1) / block;  // 16384
    TemporalDecay_89524298318172_kernel<<<grid, block, 0, stream>>>(
        h_a, deltas, M, W, bias, out);
}

// Round 3
// 145.971 us; speedup vs baseline: 1.0303x; 1.0303x over previous
//
#include <hip/hip_runtime.h>

// B=32, T=2048, D=64, K=4, KD=256
// out[b,t,j] = m*ha + (1-m)*(g*h_fwd + (1-g)*ha)
//   d = j % 64, m = M[b,t,d], delta = deltas[b,t,d] in {1,2,3,4} (clamped <= t+1)
//   g = exp(-relu(delta*W[j] + b[j]))
//   h_fwd = h_a[b, t-(int(delta)-1), j]  -> one of rows t, t-1, t-2, t-3
//
// Key trick: delta only ever points 0..3 rows back, so instead of a gather
// whose address depends on a just-loaded value (two chained memory latencies),
// load all 4 candidate rows at addresses known up-front and select per element.
// Rows t-1..t-3 are L1/L2 hits (they're other waves' streaming rows).

#define TD_T 2048
#define TD_KD 256
#define TD_D 64

typedef float f32x4 __attribute__((ext_vector_type(4)));

__global__ __launch_bounds__(256) void TemporalDecay_89524298318172_kernel(
    const float* __restrict__ h_a,
    const float* __restrict__ deltas,
    const float* __restrict__ M,
    const float* __restrict__ W,
    const float* __restrict__ bias,
    float* __restrict__ out)
{
    const int gid = blockIdx.x * blockDim.x + threadIdx.x;
    const int q   = gid & 63;        // which float4 within the 256-wide row
    const int row = gid >> 6;        // b*T + t
    const int t   = row & (TD_T - 1);
    const int j0  = q << 2;          // 0..252, multiple of 4
    const int d0  = j0 & (TD_D - 1); // no wrap inside a float4 (4 | 64)

    const size_t row_off = (size_t)row * TD_KD + j0;

    // All loads issue with no inter-load dependencies.
    const f32x4 ha4 = *(const f32x4*)(h_a    + row_off);
    const f32x4 m4  = *(const f32x4*)(M      + (size_t)row * TD_D + d0);
    const f32x4 dl4 = *(const f32x4*)(deltas + (size_t)row * TD_D + d0);
    const f32x4 w4  = *(const f32x4*)(W    + j0);
    const f32x4 b4  = *(const f32x4*)(bias + j0);

    // Candidate rows t-1, t-2, t-3 (clamped; unselected when t-r < 0 since
    // delta <= t+1 guarantees the selected row index is >= 0).
    const int r1 = (t >= 1) ? t - 1 : 0;
    const int r2 = (t >= 2) ? t - 2 : 0;
    const int r3 = (t >= 3) ? t - 3 : 0;
    const size_t bt_base = (size_t)(row - t) * TD_KD + j0;  // b*T*KD + j0
    const f32x4 c1 = *(const f32x4*)(h_a + bt_base + (size_t)r1 * TD_KD);
    const f32x4 c2 = *(const f32x4*)(h_a + bt_base + (size_t)r2 * TD_KD);
    const f32x4 c3 = *(const f32x4*)(h_a + bt_base + (size_t)r3 * TD_KD);

    f32x4 res;
#pragma unroll
    for (int e = 0; e < 4; ++e) {
        const float delta = dl4[e];
        const float g = __expf(-fmaxf(fmaf(delta, w4[e], b4[e]), 0.0f));
        const int di = (int)delta;  // 1..4
        float hf = ha4[e];
        hf = (di == 2) ? c1[e] : hf;
        hf = (di == 3) ? c2[e] : hf;
        hf = (di == 4) ? c3[e] : hf;
        const float m = m4[e];
        res[e] = m * ha4[e] + (1.0f - m) * (g * hf + (1.0f - g) * ha4[e]);
    }

    __builtin_nontemporal_store(res, (f32x4*)(out + row_off));
}

extern "C" void kernel_launch(void* const* d_in, const int* in_sizes, int n_in,
                              void* d_out, int out_size, void* d_ws, size_t ws_size,
                              hipStream_t stream) {
    const float* h_a    = (const float*)d_in[0];
    const float* deltas = (const float*)d_in[1];
    const float* M      = (const float*)d_in[2];
    const float* W      = (const float*)d_in[3];
    const float* bias   = (const float*)d_in[4];
    float* out          = (float*)d_out;

    // total float4 threads = B*T*KD/4 = 4,194,304
    const int total = in_sizes[0] / 4;
    const int block = 256;
    const int grid = (total + block - 1) / block;  // 16384
    TemporalDecay_89524298318172_kernel<<<grid, block, 0, stream>>>(
        h_a, deltas, M, W, bias, out);
}